// Round 1
// baseline (939.741 us; speedup 1.0000x reference)
//
#include <hip/hip_runtime.h>
#include <hip/hip_bf16.h>

typedef unsigned short u16;
typedef unsigned int   u32;
typedef __bf16 bf16x8 __attribute__((ext_vector_type(8)));
typedef float  f32x4  __attribute__((ext_vector_type(4)));

#define SEQ   2304
#define DM    3072
#define NH    24
#define HD    128
#define S_TXT 256
#define S_IMG 2048
#define SCALE 0.08838834764831845f  // 1/sqrt(128)

__device__ __forceinline__ u16 f2bf(float x) {  // RNE fp32->bf16
  u32 u = __float_as_uint(x);
  u += 0x7fffu + ((u >> 16) & 1u);
  return (u16)(u >> 16);
}
__device__ __forceinline__ float bf2f(u16 b) {
  return __uint_as_float(((u32)b) << 16);
}
__device__ __forceinline__ f32x4 zero4() { f32x4 z = {0.f, 0.f, 0.f, 0.f}; return z; }

// async global->LDS, 16B/lane; LDS dest is wave-uniform base + lane*16 (linear).
#define GLDS16(gp, lp) __builtin_amdgcn_global_load_lds( \
    (__attribute__((address_space(1))) void*)(gp),       \
    (__attribute__((address_space(3))) void*)(lp), 16, 0, 0)

// ---------------- fp32 -> bf16 elementwise ----------------
__global__ __launch_bounds__(256) void conv_bf16_k(const float* __restrict__ src,
                                                   u16* __restrict__ dst, int n4) {
  int i = blockIdx.x * 256 + threadIdx.x;
  if (i >= n4) return;
  float4 v = ((const float4*)src)[i];
  ushort4 o;
  o.x = f2bf(v.x); o.y = f2bf(v.y); o.z = f2bf(v.z); o.w = f2bf(v.w);
  ((ushort4*)dst)[i] = o;
}

// ---------------- weight fp32 [K][N] -> bf16 [N][K] (transpose) ----------------
struct WP { const float* s[8]; u16* d[8]; };

__global__ __launch_bounds__(256) void w_transpose_k(WP p) {
  __shared__ float tile[32][33];
  const float* __restrict__ src = p.s[blockIdx.z];
  u16* __restrict__ dst = p.d[blockIdx.z];
  const int c0 = blockIdx.x * 32, r0 = blockIdx.y * 32;
  const int tx = threadIdx.x & 31, ty = threadIdx.x >> 5;
#pragma unroll
  for (int i = 0; i < 4; ++i)
    tile[ty + i*8][tx] = src[(size_t)(r0 + ty + i*8) * DM + c0 + tx];
  __syncthreads();
#pragma unroll
  for (int i = 0; i < 4; ++i)
    dst[(size_t)(c0 + ty + i*8) * DM + r0 + tx] = f2bf(tile[tx][ty + i*8]);
}

// ---------------- bf16 V [24][2304][128] -> Vt [24][128][2304] ----------------
__global__ __launch_bounds__(256) void v_transpose_k(const u16* __restrict__ V,
                                                     u16* __restrict__ Vt) {
  __shared__ u16 tile[32][34];
  const int h = blockIdx.z;
  const int t0 = blockIdx.x * 32, d0 = blockIdx.y * 32;
  const int tx = threadIdx.x & 31, ty = threadIdx.x >> 5;
#pragma unroll
  for (int i = 0; i < 4; ++i)
    tile[ty + i*8][tx] = V[((size_t)h * SEQ + t0 + ty + i*8) * HD + d0 + tx];
  __syncthreads();
#pragma unroll
  for (int i = 0; i < 4; ++i)
    Vt[((size_t)h * HD + d0 + ty + i*8) * SEQ + t0 + tx] = tile[tx][ty + i*8];
}

// ---------------- GEMM: C[M][3072] = A[M][3072] x Bt[3072][3072]^T ----------------
// A, Bt bf16 row-major K-contiguous. 128x128 tile, BK=64, 4 waves (2x2), 16x16x32 MFMA.
// LDS tiles [128 rows][128B] with XOR swizzle byte^=((row&7)<<4): linear LDS dest +
// pre-swizzled global source (involution), swizzled ds_read -> 2-way (free) conflicts.
// mode 0: out bf16 head-split [24][2304][128] at token row_off+m (head = blockIdx.y)
// mode 1: out fp32 flat [M][3072] (+bias)
__global__ __launch_bounds__(256) void gemm_bt_k(
    const u16* __restrict__ A,
    const u16* __restrict__ B0, const u16* __restrict__ B1, const u16* __restrict__ B2,
    const float* __restrict__ bias0, const float* __restrict__ bias1, const float* __restrict__ bias2,
    void* __restrict__ out0, void* __restrict__ out1, void* __restrict__ out2,
    int row_off, int mode) {
  __shared__ __attribute__((aligned(128))) char As[128*128];
  __shared__ __attribute__((aligned(128))) char Bs[128*128];
  const int bz = blockIdx.z;
  const u16* __restrict__ Bm = (bz == 0) ? B0 : ((bz == 1) ? B1 : B2);
  const float* __restrict__ bias = (bz == 0) ? bias0 : ((bz == 1) ? bias1 : bias2);
  void* out = (bz == 0) ? out0 : ((bz == 1) ? out1 : out2);
  const int bm = blockIdx.x, bn = blockIdx.y;
  const int tid = threadIdx.x;
  const int w = tid >> 6, l = tid & 63;
  const int wr = w >> 1, wc = w & 1;

  f32x4 acc[4][4];
#pragma unroll
  for (int mi = 0; mi < 4; ++mi)
#pragma unroll
    for (int ni = 0; ni < 4; ++ni) acc[mi][ni] = zero4();

  // staging: per wave 32 rows (4 issues x 8 rows); lane -> (row=l>>3, slot=l&7)
  const int srow  = l >> 3;
  const int scolb = ((l & 7) ^ srow) << 4;  // pre-swizzled source col byte
  const char* Ag = (const char*)(A  + (size_t)(bm*128 + w*32) * DM) + (size_t)srow * (DM*2) + scolb;
  const char* Bg = (const char*)(Bm + (size_t)(bn*128 + w*32) * DM) + (size_t)srow * (DM*2) + scolb;
  char* AsW = As + (w*32) * 128;
  char* BsW = Bs + (w*32) * 128;

  for (int kt = 0; kt < DM/64; ++kt) {
#pragma unroll
    for (int i = 0; i < 4; ++i) {
      GLDS16(Ag + (size_t)i*8*(DM*2) + kt*128, AsW + i*8*128);
      GLDS16(Bg + (size_t)i*8*(DM*2) + kt*128, BsW + i*8*128);
    }
    __syncthreads();
#pragma unroll
    for (int kk = 0; kk < 2; ++kk) {
      bf16x8 af[4], bfr[4];
#pragma unroll
      for (int mi = 0; mi < 4; ++mi) {
        const int row = wr*64 + mi*16 + (l & 15);
        const int cb  = ((kk << 6) + ((l >> 4) << 4)) ^ ((row & 7) << 4);
        af[mi] = *(const bf16x8*)(As + row*128 + cb);
      }
#pragma unroll
      for (int ni = 0; ni < 4; ++ni) {
        const int row = wc*64 + ni*16 + (l & 15);
        const int cb  = ((kk << 6) + ((l >> 4) << 4)) ^ ((row & 7) << 4);
        bfr[ni] = *(const bf16x8*)(Bs + row*128 + cb);
      }
#pragma unroll
      for (int mi = 0; mi < 4; ++mi)
#pragma unroll
        for (int ni = 0; ni < 4; ++ni)
          acc[mi][ni] = __builtin_amdgcn_mfma_f32_16x16x32_bf16(af[mi], bfr[ni], acc[mi][ni], 0, 0, 0);
    }
    __syncthreads();
  }

  // epilogue: C row = (l>>4)*4+r, col = l&15 (m89-verified layout)
#pragma unroll
  for (int mi = 0; mi < 4; ++mi) {
    const int mbase = bm*128 + wr*64 + mi*16 + ((l >> 4) << 2);
#pragma unroll
    for (int ni = 0; ni < 4; ++ni) {
      const int ncol = bn*128 + wc*64 + ni*16 + (l & 15);
      const float bv = bias ? bias[ncol] : 0.f;
#pragma unroll
      for (int r = 0; r < 4; ++r) {
        const float v = acc[mi][ni][r] + bv;
        if (mode == 0) {
          ((u16*)out)[((size_t)bn * SEQ + (row_off + mbase + r)) * HD + (ncol & 127)] = f2bf(v);
        } else {
          ((float*)out)[(size_t)(mbase + r) * DM + ncol] = v;
        }
      }
    }
  }
}

// ---------------- fused per-head RMSNorm + RoPE, bf16 out ----------------
// one wave per (q|k, head, token) row of 128; Q additionally pre-scaled by 1/sqrt(128)
__global__ __launch_bounds__(256) void qk_norm_rope_k(
    const u16* __restrict__ Qf, const u16* __restrict__ Kf,
    u16* __restrict__ Qb, u16* __restrict__ Kb,
    const float* __restrict__ cosT, const float* __restrict__ sinT,
    const float* __restrict__ nq, const float* __restrict__ nk,
    const float* __restrict__ naq, const float* __restrict__ nak) {
  const int gw = (blockIdx.x * 256 + threadIdx.x) >> 6;
  const int l = threadIdx.x & 63;
  const int which = (gw >= NH * SEQ) ? 1 : 0;
  const int rem = which ? (gw - NH * SEQ) : gw;
  const int h = rem / SEQ, t = rem % SEQ;
  const size_t base = ((size_t)h * SEQ + t) * HD + l * 2;
  const ushort2 xb = *(const ushort2*)((which ? Kf : Qf) + base);
  const float x0 = bf2f(xb.x), x1 = bf2f(xb.y);
  float ss = x0*x0 + x1*x1;
#pragma unroll
  for (int msk = 1; msk < 64; msk <<= 1) ss += __shfl_xor(ss, msk, 64);
  const float rr = rsqrtf(ss * (1.0f/128.0f) + 1e-6f);
  const float* nw = which ? (t < S_TXT ? nak : nk) : (t < S_TXT ? naq : nq);
  const float n0 = x0 * rr * nw[l*2], n1 = x1 * rr * nw[l*2 + 1];
  const float c = cosT[(size_t)t * HD + l*2], sn = sinT[(size_t)t * HD + l*2];
  float o0 = n0 * c - n1 * sn;
  float o1 = n1 * c + n0 * sn;
  if (!which) { o0 *= SCALE; o1 *= SCALE; }
  ushort2 ob; ob.x = f2bf(o0); ob.y = f2bf(o1);
  *(ushort2*)((which ? Kb : Qb) + base) = ob;
}

// ---------------- flash attention ----------------
// grid (SEQ/64, NH); 4 waves, wave w owns Q rows [qt*64+w*16, +16).
// Q[24][2304][128] (pre-scaled), K[24][2304][128], Vt[24][128][2304], O[2304][3072] bf16.
__global__ __launch_bounds__(256) void attn_k(
    const u16* __restrict__ Q, const u16* __restrict__ K,
    const u16* __restrict__ Vt, u16* __restrict__ O) {
  __shared__ __attribute__((aligned(128))) char Kl[64*256];   // K tile, swizzled
  __shared__ __attribute__((aligned(128))) char Vl[128*128];  // Vt tile, swizzled
  __shared__ __attribute__((aligned(128))) char Pl[4][2048];  // per-wave P, swizzled
  const int qt = blockIdx.x, h = blockIdx.y;
  const int tid = threadIdx.x, w = tid >> 6, l = tid & 63;

  const u16* Qh = Q  + ((size_t)h * SEQ + qt*64 + w*16) * HD;
  const u16* Kh = K  + (size_t)h * SEQ * HD;
  const u16* Vh = Vt + (size_t)h * HD * SEQ;

  bf16x8 qf[4];  // A-frag: row = l&15, k = kf*32 + (l>>4)*8
#pragma unroll
  for (int kf = 0; kf < 4; ++kf)
    qf[kf] = *(const bf16x8*)(Qh + (l & 15) * HD + kf*32 + ((l >> 4) << 3));

  f32x4 o[8];
#pragma unroll
  for (int db = 0; db < 8; ++db) o[db] = zero4();
  float m[4]  = {-1e30f, -1e30f, -1e30f, -1e30f};
  float rl[4] = {0.f, 0.f, 0.f, 0.f};

  const int vswz = ((l & 7) ^ (l >> 3)) << 4;  // Vt stage source col byte

  for (int kb = 0; kb < SEQ/64; ++kb) {
    // stage K tile: 64 rows x 256B; per wave 16 rows, 4 issues x 4 rows
#pragma unroll
    for (int i = 0; i < 4; ++i) {
      const int rloc = i*4 + (l >> 4);
      const int colb = ((l & 15) << 4) ^ ((rloc & 7) << 4);
      GLDS16((const char*)Kh + ((size_t)(kb*64 + w*16 + rloc)) * 256 + colb,
             Kl + (w*16 + i*4) * 256);
    }
    // stage Vt tile: 128 rows x 128B; per wave 32 rows, 4 issues x 8 rows
#pragma unroll
    for (int i = 0; i < 4; ++i) {
      const int rloc = w*32 + i*8 + (l >> 3);
      GLDS16((const char*)Vh + (size_t)rloc * (SEQ*2) + kb*128 + vswz,
             Vl + (w*32 + i*8) * 128);
    }
    __syncthreads();

    // S = Q K^T  (B-frag: col = l&15 -> kv idx, k = d contiguous)
    f32x4 s[4];
#pragma unroll
    for (int ni = 0; ni < 4; ++ni) {
      f32x4 a = zero4();
      const int row = ni*16 + (l & 15);
#pragma unroll
      for (int kf = 0; kf < 4; ++kf) {
        const int cb = ((kf << 6) + ((l >> 4) << 4)) ^ ((row & 7) << 4);
        bf16x8 kfr = *(const bf16x8*)(Kl + row*256 + cb);
        a = __builtin_amdgcn_mfma_f32_16x16x32_bf16(qf[kf], kfr, a, 0, 0, 0);
      }
      s[ni] = a;
    }

    // online softmax; C row = (l>>4)*4+r lives in 16 lanes (vary l&15)
    float mnew[4], resc[4];
#pragma unroll
    for (int r = 0; r < 4; ++r) {
      float mx = fmaxf(fmaxf(s[0][r], s[1][r]), fmaxf(s[2][r], s[3][r]));
#pragma unroll
      for (int msk = 1; msk < 16; msk <<= 1) mx = fmaxf(mx, __shfl_xor(mx, msk, 64));
      mnew[r] = fmaxf(m[r], mx);
      resc[r] = __expf(m[r] - mnew[r]);
      m[r] = mnew[r];
    }
#pragma unroll
    for (int ni = 0; ni < 4; ++ni) {
      f32x4 t = s[ni];
#pragma unroll
      for (int r = 0; r < 4; ++r) t[r] = __expf(t[r] - m[r]);
      s[ni] = t;
    }
#pragma unroll
    for (int r = 0; r < 4; ++r) {
      float t = s[0][r] + s[1][r] + s[2][r] + s[3][r];
#pragma unroll
      for (int msk = 1; msk < 16; msk <<= 1) t += __shfl_xor(t, msk, 64);
      rl[r] = rl[r] * resc[r] + t;
    }
#pragma unroll
    for (int db = 0; db < 8; ++db) {
      f32x4 t = o[db];
#pragma unroll
      for (int r = 0; r < 4; ++r) t[r] *= resc[r];
      o[db] = t;
    }

    // P (C layout) -> bf16 -> per-wave LDS (swizzled), then read as A-frag
    char* Pw = Pl[w];
#pragma unroll
    for (int ni = 0; ni < 4; ++ni)
#pragma unroll
      for (int r = 0; r < 4; ++r) {
        const int prow = ((l >> 4) << 2) + r;
        const int pcb  = ((ni*16 + (l & 15)) << 1) ^ ((prow & 7) << 4);
        *(u16*)(Pw + prow*128 + pcb) = f2bf(s[ni][r]);
      }

    // O += P V : A = P[m][n], B-frag from Vt (col = l&15 -> d, k = n contiguous)
    const int arow = l & 15;
#pragma unroll
    for (int kblk = 0; kblk < 2; ++kblk) {
      const int pcb = ((kblk << 6) + ((l >> 4) << 4)) ^ ((arow & 7) << 4);
      bf16x8 pa = *(const bf16x8*)(Pw + arow*128 + pcb);
#pragma unroll
      for (int db = 0; db < 8; ++db) {
        const int vrow = db*16 + (l & 15);
        const int vcb  = ((kblk << 6) + ((l >> 4) << 4)) ^ ((vrow & 7) << 4);
        bf16x8 vb = *(const bf16x8*)(Vl + vrow*128 + vcb);
        o[db] = __builtin_amdgcn_mfma_f32_16x16x32_bf16(pa, vb, o[db], 0, 0, 0);
      }
    }
    __syncthreads();
  }

#pragma unroll
  for (int r = 0; r < 4; ++r) rl[r] = 1.f / rl[r];
#pragma unroll
  for (int db = 0; db < 8; ++db)
#pragma unroll
    for (int r = 0; r < 4; ++r) {
      const int token = qt*64 + w*16 + ((l >> 4) << 2) + r;
      const int col = h*HD + db*16 + (l & 15);
      O[(size_t)token * DM + col] = f2bf(o[db][r] * rl[r]);
    }
}

// ---------------- host ----------------
extern "C" void kernel_launch(void* const* d_in, const int* in_sizes, int n_in,
                              void* d_out, int out_size, void* d_ws, size_t ws_size,
                              hipStream_t stream) {
  const float* hidden = (const float*)d_in[0];
  const float* ench   = (const float*)d_in[1];
  const float* cosT   = (const float*)d_in[2];
  const float* sinT   = (const float*)d_in[3];
  const float* wq  = (const float*)d_in[4];
  const float* wk  = (const float*)d_in[5];
  const float* wv  = (const float*)d_in[6];
  const float* wqa = (const float*)d_in[7];
  const float* wka = (const float*)d_in[8];
  const float* wva = (const float*)d_in[9];
  const float* bqa = (const float*)d_in[10];
  const float* bka = (const float*)d_in[11];
  const float* bva = (const float*)d_in[12];
  const float* nq  = (const float*)d_in[13];
  const float* nk  = (const float*)d_in[14];
  const float* naq = (const float*)d_in[15];
  const float* nak = (const float*)d_in[16];
  const float* w_out     = (const float*)d_in[17];
  const float* b_out     = (const float*)d_in[18];
  const float* w_add_out = (const float*)d_in[19];
  const float* b_add_out = (const float*)d_in[20];
  float* outp = (float*)d_out;
  (void)in_sizes; (void)n_in; (void)out_size; (void)ws_size;

  char* ws = (char*)d_ws;
  size_t off = 0;
  auto alloc = [&](size_t n) { char* p = ws + off; off += (n + 255) & ~(size_t)255; return p; };
  u16* wt[8];
  for (int i = 0; i < 8; ++i) wt[i] = (u16*)alloc((size_t)DM * DM * 2);
  u16* xb_img = (u16*)alloc((size_t)S_IMG * DM * 2);
  u16* xb_enc = (u16*)alloc((size_t)S_TXT * DM * 2);
  u16* Qf = (u16*)alloc((size_t)NH * SEQ * HD * 2);
  u16* Kf = (u16*)alloc((size_t)NH * SEQ * HD * 2);
  u16* Vf = (u16*)alloc((size_t)NH * SEQ * HD * 2);
  u16* Qb = (u16*)alloc((size_t)NH * SEQ * HD * 2);
  u16* Kb = (u16*)alloc((size_t)NH * SEQ * HD * 2);
  u16* Vt = (u16*)alloc((size_t)NH * HD * SEQ * 2);
  u16* Ob = (u16*)alloc((size_t)SEQ * DM * 2);

  conv_bf16_k<<<(S_IMG*DM/4)/256, 256, 0, stream>>>(hidden, xb_img, S_IMG*DM/4);
  conv_bf16_k<<<(S_TXT*DM/4)/256, 256, 0, stream>>>(ench, xb_enc, S_TXT*DM/4);

  WP wp;
  wp.s[0] = wq;  wp.s[1] = wk;  wp.s[2] = wv;
  wp.s[3] = wqa; wp.s[4] = wka; wp.s[5] = wva;
  wp.s[6] = w_out; wp.s[7] = w_add_out;
  for (int i = 0; i < 8; ++i) wp.d[i] = wt[i];
  w_transpose_k<<<dim3(96, 96, 8), 256, 0, stream>>>(wp);

  // QKV projections (z: 0=q,1=k,2=v), head-split bf16 out; enc tokens are rows [0,256)
  gemm_bt_k<<<dim3(16, 24, 3), 256, 0, stream>>>(xb_img, wt[0], wt[1], wt[2],
      nullptr, nullptr, nullptr, Qf, Kf, Vf, S_TXT, 0);
  gemm_bt_k<<<dim3(2, 24, 3), 256, 0, stream>>>(xb_enc, wt[3], wt[4], wt[5],
      bqa, bka, bva, Qf, Kf, Vf, 0, 0);

  qk_norm_rope_k<<<(2*NH*SEQ)/4, 256, 0, stream>>>(Qf, Kf, Qb, Kb, cosT, sinT, nq, nk, naq, nak);
  v_transpose_k<<<dim3(SEQ/32, HD/32, NH), 256, 0, stream>>>(Vf, Vt);

  attn_k<<<dim3(SEQ/64, NH), 256, 0, stream>>>(Qb, Kb, Vt, Ob);

  // output projections: img tokens (rows 256..2303) -> d_out[0:2048*3072], enc -> tail
  gemm_bt_k<<<dim3(16, 24, 1), 256, 0, stream>>>(Ob + (size_t)S_TXT * DM, wt[6], wt[6], wt[6],
      b_out, b_out, b_out, outp, outp, outp, 0, 1);
  gemm_bt_k<<<dim3(2, 24, 1), 256, 0, stream>>>(Ob, wt[7], wt[7], wt[7],
      b_add_out, b_add_out, b_add_out,
      outp + (size_t)S_IMG * DM, outp + (size_t)S_IMG * DM, outp + (size_t)S_IMG * DM, 0, 1);
}

// Round 2
// 937.836 us; speedup vs baseline: 1.0020x; 1.0020x over previous
//
#include <hip/hip_runtime.h>
#include <hip/hip_bf16.h>

typedef unsigned short u16;
typedef unsigned int   u32;
typedef __bf16 bf16x8 __attribute__((ext_vector_type(8)));
typedef float  f32x4  __attribute__((ext_vector_type(4)));

#define SEQ   2304
#define DM    3072
#define NH    24
#define HD    128
#define S_TXT 256
#define S_IMG 2048
#define SCALE 0.08838834764831845f  // 1/sqrt(128)

__device__ __forceinline__ u16 f2bf(float x) {  // RNE fp32->bf16
  u32 u = __float_as_uint(x);
  u += 0x7fffu + ((u >> 16) & 1u);
  return (u16)(u >> 16);
}
__device__ __forceinline__ float bf2f(u16 b) {
  return __uint_as_float(((u32)b) << 16);
}
__device__ __forceinline__ f32x4 zero4() { f32x4 z = {0.f, 0.f, 0.f, 0.f}; return z; }
__device__ __forceinline__ u32 cvtpk(float lo, float hi) {
  u32 r;
  asm("v_cvt_pk_bf16_f32 %0, %1, %2" : "=v"(r) : "v"(lo), "v"(hi));
  return r;
}

// async global->LDS, 16B/lane; LDS dest is wave-uniform base + lane*16 (linear).
#define GLDS16(gp, lp) __builtin_amdgcn_global_load_lds( \
    (__attribute__((address_space(1))) void*)(gp),       \
    (__attribute__((address_space(3))) void*)(lp), 16, 0, 0)

// ---------------- fp32 -> bf16 elementwise ----------------
__global__ __launch_bounds__(256) void conv_bf16_k(const float* __restrict__ src,
                                                   u16* __restrict__ dst, int n4) {
  int i = blockIdx.x * 256 + threadIdx.x;
  if (i >= n4) return;
  float4 v = ((const float4*)src)[i];
  ushort4 o;
  o.x = f2bf(v.x); o.y = f2bf(v.y); o.z = f2bf(v.z); o.w = f2bf(v.w);
  ((ushort4*)dst)[i] = o;
}

// ---------------- weight fp32 [K][N] -> bf16 [N][K] (transpose) ----------------
struct WP { const float* s[8]; u16* d[8]; };

__global__ __launch_bounds__(256) void w_transpose_k(WP p) {
  __shared__ float tile[32][33];
  const float* __restrict__ src = p.s[blockIdx.z];
  u16* __restrict__ dst = p.d[blockIdx.z];
  const int c0 = blockIdx.x * 32, r0 = blockIdx.y * 32;
  const int tx = threadIdx.x & 31, ty = threadIdx.x >> 5;
#pragma unroll
  for (int i = 0; i < 4; ++i)
    tile[ty + i*8][tx] = src[(size_t)(r0 + ty + i*8) * DM + c0 + tx];
  __syncthreads();
#pragma unroll
  for (int i = 0; i < 4; ++i)
    dst[(size_t)(c0 + ty + i*8) * DM + r0 + tx] = f2bf(tile[tx][ty + i*8]);
}

// ---------------- bf16 V [24][2304][128] -> Vt [24][128][2304] ----------------
__global__ __launch_bounds__(256) void v_transpose_k(const u16* __restrict__ V,
                                                     u16* __restrict__ Vt) {
  __shared__ u16 tile[32][34];
  const int h = blockIdx.z;
  const int t0 = blockIdx.x * 32, d0 = blockIdx.y * 32;
  const int tx = threadIdx.x & 31, ty = threadIdx.x >> 5;
#pragma unroll
  for (int i = 0; i < 4; ++i)
    tile[ty + i*8][tx] = V[((size_t)h * SEQ + t0 + ty + i*8) * HD + d0 + tx];
  __syncthreads();
#pragma unroll
  for (int i = 0; i < 4; ++i)
    Vt[((size_t)h * HD + d0 + ty + i*8) * SEQ + t0 + tx] = tile[tx][ty + i*8];
}

// ---------------- GEMM: C[M][3072] = A[M][3072] x Bt[3072][3072]^T ----------------
// (unchanged from R1 — passed; 128x128 tile, BK=64, swizzled global_load_lds)
__global__ __launch_bounds__(256) void gemm_bt_k(
    const u16* __restrict__ A,
    const u16* __restrict__ B0, const u16* __restrict__ B1, const u16* __restrict__ B2,
    const float* __restrict__ bias0, const float* __restrict__ bias1, const float* __restrict__ bias2,
    void* __restrict__ out0, void* __restrict__ out1, void* __restrict__ out2,
    int row_off, int mode) {
  __shared__ __attribute__((aligned(128))) char As[128*128];
  __shared__ __attribute__((aligned(128))) char Bs[128*128];
  const int bz = blockIdx.z;
  const u16* __restrict__ Bm = (bz == 0) ? B0 : ((bz == 1) ? B1 : B2);
  const float* __restrict__ bias = (bz == 0) ? bias0 : ((bz == 1) ? bias1 : bias2);
  void* out = (bz == 0) ? out0 : ((bz == 1) ? out1 : out2);
  const int bm = blockIdx.x, bn = blockIdx.y;
  const int tid = threadIdx.x;
  const int w = tid >> 6, l = tid & 63;
  const int wr = w >> 1, wc = w & 1;

  f32x4 acc[4][4];
#pragma unroll
  for (int mi = 0; mi < 4; ++mi)
#pragma unroll
    for (int ni = 0; ni < 4; ++ni) acc[mi][ni] = zero4();

  const int srow  = l >> 3;
  const int scolb = ((l & 7) ^ srow) << 4;
  const char* Ag = (const char*)(A  + (size_t)(bm*128 + w*32) * DM) + (size_t)srow * (DM*2) + scolb;
  const char* Bg = (const char*)(Bm + (size_t)(bn*128 + w*32) * DM) + (size_t)srow * (DM*2) + scolb;
  char* AsW = As + (w*32) * 128;
  char* BsW = Bs + (w*32) * 128;

  for (int kt = 0; kt < DM/64; ++kt) {
#pragma unroll
    for (int i = 0; i < 4; ++i) {
      GLDS16(Ag + (size_t)i*8*(DM*2) + kt*128, AsW + i*8*128);
      GLDS16(Bg + (size_t)i*8*(DM*2) + kt*128, BsW + i*8*128);
    }
    __syncthreads();
#pragma unroll
    for (int kk = 0; kk < 2; ++kk) {
      bf16x8 af[4], bfr[4];
#pragma unroll
      for (int mi = 0; mi < 4; ++mi) {
        const int row = wr*64 + mi*16 + (l & 15);
        const int cb  = ((kk << 6) + ((l >> 4) << 4)) ^ ((row & 7) << 4);
        af[mi] = *(const bf16x8*)(As + row*128 + cb);
      }
#pragma unroll
      for (int ni = 0; ni < 4; ++ni) {
        const int row = wc*64 + ni*16 + (l & 15);
        const int cb  = ((kk << 6) + ((l >> 4) << 4)) ^ ((row & 7) << 4);
        bfr[ni] = *(const bf16x8*)(Bs + row*128 + cb);
      }
#pragma unroll
      for (int mi = 0; mi < 4; ++mi)
#pragma unroll
        for (int ni = 0; ni < 4; ++ni)
          acc[mi][ni] = __builtin_amdgcn_mfma_f32_16x16x32_bf16(af[mi], bfr[ni], acc[mi][ni], 0, 0, 0);
    }
    __syncthreads();
  }

#pragma unroll
  for (int mi = 0; mi < 4; ++mi) {
    const int mbase = bm*128 + wr*64 + mi*16 + ((l >> 4) << 2);
#pragma unroll
    for (int ni = 0; ni < 4; ++ni) {
      const int ncol = bn*128 + wc*64 + ni*16 + (l & 15);
      const float bv = bias ? bias[ncol] : 0.f;
#pragma unroll
      for (int r = 0; r < 4; ++r) {
        const float v = acc[mi][ni][r] + bv;
        if (mode == 0) {
          ((u16*)out)[((size_t)bn * SEQ + (row_off + mbase + r)) * HD + (ncol & 127)] = f2bf(v);
        } else {
          ((float*)out)[(size_t)(mbase + r) * DM + ncol] = v;
        }
      }
    }
  }
}

// ---------------- fused per-head RMSNorm + RoPE, bf16 out ----------------
__global__ __launch_bounds__(256) void qk_norm_rope_k(
    const u16* __restrict__ Qf, const u16* __restrict__ Kf,
    u16* __restrict__ Qb, u16* __restrict__ Kb,
    const float* __restrict__ cosT, const float* __restrict__ sinT,
    const float* __restrict__ nq, const float* __restrict__ nk,
    const float* __restrict__ naq, const float* __restrict__ nak) {
  const int gw = (blockIdx.x * 256 + threadIdx.x) >> 6;
  const int l = threadIdx.x & 63;
  const int which = (gw >= NH * SEQ) ? 1 : 0;
  const int rem = which ? (gw - NH * SEQ) : gw;
  const int h = rem / SEQ, t = rem % SEQ;
  const size_t base = ((size_t)h * SEQ + t) * HD + l * 2;
  const ushort2 xb = *(const ushort2*)((which ? Kf : Qf) + base);
  const float x0 = bf2f(xb.x), x1 = bf2f(xb.y);
  float ss = x0*x0 + x1*x1;
#pragma unroll
  for (int msk = 1; msk < 64; msk <<= 1) ss += __shfl_xor(ss, msk, 64);
  const float rr = rsqrtf(ss * (1.0f/128.0f) + 1e-6f);
  const float* nw = which ? (t < S_TXT ? nak : nk) : (t < S_TXT ? naq : nq);
  const float n0 = x0 * rr * nw[l*2], n1 = x1 * rr * nw[l*2 + 1];
  const float c = cosT[(size_t)t * HD + l*2], sn = sinT[(size_t)t * HD + l*2];
  float o0 = n0 * c - n1 * sn;
  float o1 = n1 * c + n0 * sn;
  if (!which) { o0 *= SCALE; o1 *= SCALE; }
  ushort2 ob; ob.x = f2bf(o0); ob.y = f2bf(o1);
  *(ushort2*)((which ? Kb : Qb) + base) = ob;
}

// ---------------- flash attention v2 ----------------
// grid (SEQ/128, NH); 4 waves; wave w owns q rows [qb*128 + w*32, +32) (2 q-tiles).
// Swapped QK^T: S^T = mfma(K, Q) so each lane holds a kv-contiguous P row for
// q = l&15 -> in-lane softmax reduce + b64 P writes (swizzled, conflict-free).
// Q[24][2304][128] (pre-scaled), K[24][2304][128], Vt[24][128][2304], O[2304][3072] bf16.
__global__ __launch_bounds__(256) void attn_k(
    const u16* __restrict__ Q, const u16* __restrict__ K,
    const u16* __restrict__ Vt, u16* __restrict__ O) {
  __shared__ __attribute__((aligned(128))) char Kl[64*256];      // K tile, swizzled
  __shared__ __attribute__((aligned(128))) char Vl[128*128];     // Vt tile, swizzled
  __shared__ __attribute__((aligned(128))) char Pl[4][2][2048];  // per-wave,per-qt P[16q][64kv]
  const int qb = blockIdx.x, h = blockIdx.y;
  const int tid = threadIdx.x, w = tid >> 6, l = tid & 63;
  const int g = l >> 4, q16 = l & 15;

  const u16* Qh = Q  + ((size_t)h * SEQ + qb*128 + w*32) * HD;
  const u16* Kh = K  + (size_t)h * SEQ * HD;
  const u16* Vh = Vt + (size_t)h * HD * SEQ;

  // Q as B-frag: col = q16 (q row), k = kf*32 + g*8 contiguous d
  bf16x8 qf[2][4];
#pragma unroll
  for (int qt = 0; qt < 2; ++qt)
#pragma unroll
    for (int kf = 0; kf < 4; ++kf)
      qf[qt][kf] = *(const bf16x8*)(Qh + (qt*16 + q16) * HD + kf*32 + g*8);

  f32x4 o[2][8];
#pragma unroll
  for (int qt = 0; qt < 2; ++qt)
#pragma unroll
    for (int db = 0; db < 8; ++db) o[qt][db] = zero4();
  float m[2]  = {-3e38f, -3e38f};
  float rl[2] = {0.f, 0.f};

  const int vswz = ((l & 7) ^ (l >> 3)) << 4;
  const int pswz = (q16 & 7) << 4;

  for (int kb = 0; kb < SEQ/64; ++kb) {
    // stage K tile: 64 rows x 256B; per wave 16 rows (4 issues x 4 rows)
#pragma unroll
    for (int i = 0; i < 4; ++i) {
      const int rloc = i*4 + (l >> 4);
      const int colb = ((l & 15) << 4) ^ ((rloc & 7) << 4);
      GLDS16((const char*)Kh + ((size_t)(kb*64 + w*16 + rloc)) * 256 + colb,
             Kl + (w*16 + i*4) * 256);
    }
    // stage Vt tile: 128 rows x 128B; per wave 32 rows (4 issues x 8 rows)
#pragma unroll
    for (int i = 0; i < 4; ++i) {
      const int rloc = w*32 + i*8 + (l >> 3);
      GLDS16((const char*)Vh + (size_t)rloc * (SEQ*2) + kb*128 + vswz,
             Vl + (w*32 + i*8) * 128);
    }
    __syncthreads();

    // S^T[kv][q] = K · Q^T ; K frags shared across both q-tiles
    f32x4 s[2][4];
#pragma unroll
    for (int qt = 0; qt < 2; ++qt)
#pragma unroll
      for (int mi = 0; mi < 4; ++mi) s[qt][mi] = zero4();
#pragma unroll
    for (int mi = 0; mi < 4; ++mi) {
      const int row = mi*16 + q16;
      bf16x8 kfr[4];
#pragma unroll
      for (int kf = 0; kf < 4; ++kf) {
        const int cb = ((kf << 6) + (g << 4)) ^ ((row & 7) << 4);
        kfr[kf] = *(const bf16x8*)(Kl + row*256 + cb);
      }
#pragma unroll
      for (int kf = 0; kf < 4; ++kf) {
        s[0][mi] = __builtin_amdgcn_mfma_f32_16x16x32_bf16(kfr[kf], qf[0][kf], s[0][mi], 0, 0, 0);
        s[1][mi] = __builtin_amdgcn_mfma_f32_16x16x32_bf16(kfr[kf], qf[1][kf], s[1][mi], 0, 0, 0);
      }
    }

    // online softmax per q-tile: lane holds 16 kv values for q = q16
    float rsv[2];
#pragma unroll
    for (int qt = 0; qt < 2; ++qt) {
      float mx = s[qt][0][0];
#pragma unroll
      for (int mi = 0; mi < 4; ++mi)
#pragma unroll
        for (int r = 0; r < 4; ++r) mx = fmaxf(mx, s[qt][mi][r]);
      mx = fmaxf(mx, __shfl_xor(mx, 16, 64));
      mx = fmaxf(mx, __shfl_xor(mx, 32, 64));
      const float mn = fmaxf(m[qt], mx);
      rsv[qt] = __expf(m[qt] - mn);
      m[qt] = mn;
      float sum = 0.f;
#pragma unroll
      for (int mi = 0; mi < 4; ++mi) {
        f32x4 t = s[qt][mi];
#pragma unroll
        for (int r = 0; r < 4; ++r) { t[r] = __expf(t[r] - mn); sum += t[r]; }
        s[qt][mi] = t;
      }
      sum += __shfl_xor(sum, 16, 64);
      sum += __shfl_xor(sum, 32, 64);
      rl[qt] = rl[qt] * rsv[qt] + sum;
      // pack P row (bf16) and write 8B per mi, swizzled
      char* Pw = Pl[w][qt];
#pragma unroll
      for (int mi = 0; mi < 4; ++mi) {
        uint2 pk;
        pk.x = cvtpk(s[qt][mi][0], s[qt][mi][1]);
        pk.y = cvtpk(s[qt][mi][2], s[qt][mi][3]);
        *(uint2*)(Pw + ((q16*128 + mi*32 + g*8) ^ pswz)) = pk;
      }
    }

    // rescale O by resc redistributed to C-layout (q = g*4 + r)
#pragma unroll
    for (int qt = 0; qt < 2; ++qt) {
      float rs4[4];
#pragma unroll
      for (int r = 0; r < 4; ++r)
        rs4[r] = __shfl(rsv[qt], (g << 4) + (g << 2) + r, 64);
#pragma unroll
      for (int db = 0; db < 8; ++db) {
        f32x4 t = o[qt][db];
#pragma unroll
        for (int r = 0; r < 4; ++r) t[r] *= rs4[r];
        o[qt][db] = t;
      }
    }

    // P A-frags: row = q16, k = kblk*32 + g*8 contiguous
    bf16x8 pa[2][2];
#pragma unroll
    for (int qt = 0; qt < 2; ++qt)
#pragma unroll
      for (int kblk = 0; kblk < 2; ++kblk)
        pa[qt][kblk] = *(const bf16x8*)(Pl[w][qt] + ((q16*128 + kblk*64 + g*16) ^ pswz));

    // O += P · V ; Vt B-frags shared across both q-tiles
#pragma unroll
    for (int kblk = 0; kblk < 2; ++kblk)
#pragma unroll
      for (int db = 0; db < 8; ++db) {
        const int vrow = db*16 + q16;
        const int vcb  = ((kblk << 6) + (g << 4)) ^ ((vrow & 7) << 4);
        bf16x8 vb = *(const bf16x8*)(Vl + vrow*128 + vcb);
        o[0][db] = __builtin_amdgcn_mfma_f32_16x16x32_bf16(pa[0][kblk], vb, o[0][db], 0, 0, 0);
        o[1][db] = __builtin_amdgcn_mfma_f32_16x16x32_bf16(pa[1][kblk], vb, o[1][db], 0, 0, 0);
      }
    __syncthreads();
  }

  // epilogue: divide by rl (redistributed to C-layout) and store
#pragma unroll
  for (int qt = 0; qt < 2; ++qt) {
    float inv4[4];
#pragma unroll
    for (int r = 0; r < 4; ++r)
      inv4[r] = 1.f / __shfl(rl[qt], (g << 4) + (g << 2) + r, 64);
#pragma unroll
    for (int db = 0; db < 8; ++db)
#pragma unroll
      for (int r = 0; r < 4; ++r) {
        const int token = qb*128 + w*32 + qt*16 + g*4 + r;
        const int col = h*HD + db*16 + q16;
        O[(size_t)token * DM + col] = f2bf(o[qt][db][r] * inv4[r]);
      }
  }
}

// ---------------- host ----------------
extern "C" void kernel_launch(void* const* d_in, const int* in_sizes, int n_in,
                              void* d_out, int out_size, void* d_ws, size_t ws_size,
                              hipStream_t stream) {
  const float* hidden = (const float*)d_in[0];
  const float* ench   = (const float*)d_in[1];
  const float* cosT   = (const float*)d_in[2];
  const float* sinT   = (const float*)d_in[3];
  const float* wq  = (const float*)d_in[4];
  const float* wk  = (const float*)d_in[5];
  const float* wv  = (const float*)d_in[6];
  const float* wqa = (const float*)d_in[7];
  const float* wka = (const float*)d_in[8];
  const float* wva = (const float*)d_in[9];
  const float* bqa = (const float*)d_in[10];
  const float* bka = (const float*)d_in[11];
  const float* bva = (const float*)d_in[12];
  const float* nq  = (const float*)d_in[13];
  const float* nk  = (const float*)d_in[14];
  const float* naq = (const float*)d_in[15];
  const float* nak = (const float*)d_in[16];
  const float* w_out     = (const float*)d_in[17];
  const float* b_out     = (const float*)d_in[18];
  const float* w_add_out = (const float*)d_in[19];
  const float* b_add_out = (const float*)d_in[20];
  float* outp = (float*)d_out;
  (void)in_sizes; (void)n_in; (void)out_size; (void)ws_size;

  char* ws = (char*)d_ws;
  size_t off = 0;
  auto alloc = [&](size_t n) { char* p = ws + off; off += (n + 255) & ~(size_t)255; return p; };
  u16* wt[8];
  for (int i = 0; i < 8; ++i) wt[i] = (u16*)alloc((size_t)DM * DM * 2);
  u16* xb_img = (u16*)alloc((size_t)S_IMG * DM * 2);
  u16* xb_enc = (u16*)alloc((size_t)S_TXT * DM * 2);
  u16* Qf = (u16*)alloc((size_t)NH * SEQ * HD * 2);
  u16* Kf = (u16*)alloc((size_t)NH * SEQ * HD * 2);
  u16* Vf = (u16*)alloc((size_t)NH * SEQ * HD * 2);
  u16* Qb = (u16*)alloc((size_t)NH * SEQ * HD * 2);
  u16* Kb = (u16*)alloc((size_t)NH * SEQ * HD * 2);
  u16* Vt = (u16*)alloc((size_t)NH * HD * SEQ * 2);
  u16* Ob = (u16*)alloc((size_t)SEQ * DM * 2);

  conv_bf16_k<<<(S_IMG*DM/4)/256, 256, 0, stream>>>(hidden, xb_img, S_IMG*DM/4);
  conv_bf16_k<<<(S_TXT*DM/4)/256, 256, 0, stream>>>(ench, xb_enc, S_TXT*DM/4);

  WP wp;
  wp.s[0] = wq;  wp.s[1] = wk;  wp.s[2] = wv;
  wp.s[3] = wqa; wp.s[4] = wka; wp.s[5] = wva;
  wp.s[6] = w_out; wp.s[7] = w_add_out;
  for (int i = 0; i < 8; ++i) wp.d[i] = wt[i];
  w_transpose_k<<<dim3(96, 96, 8), 256, 0, stream>>>(wp);

  gemm_bt_k<<<dim3(16, 24, 3), 256, 0, stream>>>(xb_img, wt[0], wt[1], wt[2],
      nullptr, nullptr, nullptr, Qf, Kf, Vf, S_TXT, 0);
  gemm_bt_k<<<dim3(2, 24, 3), 256, 0, stream>>>(xb_enc, wt[3], wt[4], wt[5],
      bqa, bka, bva, Qf, Kf, Vf, 0, 0);

  qk_norm_rope_k<<<(2*NH*SEQ)/4, 256, 0, stream>>>(Qf, Kf, Qb, Kb, cosT, sinT, nq, nk, naq, nak);
  v_transpose_k<<<dim3(SEQ/32, HD/32, NH), 256, 0, stream>>>(Vf, Vt);

  attn_k<<<dim3(SEQ/128, NH), 256, 0, stream>>>(Qb, Kb, Vt, Ob);

  gemm_bt_k<<<dim3(16, 24, 1), 256, 0, stream>>>(Ob + (size_t)S_TXT * DM, wt[6], wt[6], wt[6],
      b_out, b_out, b_out, outp, outp, outp, 0, 1);
  gemm_bt_k<<<dim3(2, 24, 1), 256, 0, stream>>>(Ob, wt[7], wt[7], wt[7],
      b_add_out, b_add_out, b_add_out,
      outp + (size_t)S_IMG * DM, outp + (size_t)S_IMG * DM, outp + (size_t)S_IMG * DM, 0, 1);
}

// Round 3
// 781.044 us; speedup vs baseline: 1.2032x; 1.2007x over previous
//
#include <hip/hip_runtime.h>
#include <hip/hip_bf16.h>

typedef unsigned short u16;
typedef unsigned int   u32;
typedef __bf16 bf16x8 __attribute__((ext_vector_type(8)));
typedef float  f32x4  __attribute__((ext_vector_type(4)));

#define SEQ   2304
#define DM    3072
#define NH    24
#define HD    128
#define S_TXT 256
#define S_IMG 2048
#define SCALE 0.08838834764831845f  // 1/sqrt(128)

__device__ __forceinline__ u16 f2bf(float x) {  // RNE fp32->bf16
  u32 u = __float_as_uint(x);
  u += 0x7fffu + ((u >> 16) & 1u);
  return (u16)(u >> 16);
}
__device__ __forceinline__ float bf2f(u16 b) {
  return __uint_as_float(((u32)b) << 16);
}
__device__ __forceinline__ f32x4 zero4() { f32x4 z = {0.f, 0.f, 0.f, 0.f}; return z; }
__device__ __forceinline__ u32 cvtpk(float lo, float hi) {
  u32 r;
  asm("v_cvt_pk_bf16_f32 %0, %1, %2" : "=v"(r) : "v"(lo), "v"(hi));
  return r;
}

// async global->LDS, 16B/lane; LDS dest is wave-uniform base + lane*16 (linear).
#define GLDS16(gp, lp) __builtin_amdgcn_global_load_lds( \
    (__attribute__((address_space(1))) void*)(gp),       \
    (__attribute__((address_space(3))) void*)(lp), 16, 0, 0)

// ---------------- fp32 -> bf16 elementwise ----------------
__global__ __launch_bounds__(256) void conv_bf16_k(const float* __restrict__ src,
                                                   u16* __restrict__ dst, int n4) {
  int i = blockIdx.x * 256 + threadIdx.x;
  if (i >= n4) return;
  float4 v = ((const float4*)src)[i];
  ushort4 o;
  o.x = f2bf(v.x); o.y = f2bf(v.y); o.z = f2bf(v.z); o.w = f2bf(v.w);
  ((ushort4*)dst)[i] = o;
}

// ---------------- weight fp32 [K][N] -> bf16 [N][K] (transpose) ----------------
struct WP { const float* s[8]; u16* d[8]; };

__global__ __launch_bounds__(256) void w_transpose_k(WP p) {
  __shared__ float tile[32][33];
  const float* __restrict__ src = p.s[blockIdx.z];
  u16* __restrict__ dst = p.d[blockIdx.z];
  const int c0 = blockIdx.x * 32, r0 = blockIdx.y * 32;
  const int tx = threadIdx.x & 31, ty = threadIdx.x >> 5;
#pragma unroll
  for (int i = 0; i < 4; ++i)
    tile[ty + i*8][tx] = src[(size_t)(r0 + ty + i*8) * DM + c0 + tx];
  __syncthreads();
#pragma unroll
  for (int i = 0; i < 4; ++i)
    dst[(size_t)(c0 + ty + i*8) * DM + r0 + tx] = f2bf(tile[tx][ty + i*8]);
}

// ---------------- bf16 V [24][2304][128] -> Vt [24][128][2304] ----------------
__global__ __launch_bounds__(256) void v_transpose_k(const u16* __restrict__ V,
                                                     u16* __restrict__ Vt) {
  __shared__ u16 tile[32][34];
  const int h = blockIdx.z;
  const int t0 = blockIdx.x * 32, d0 = blockIdx.y * 32;
  const int tx = threadIdx.x & 31, ty = threadIdx.x >> 5;
#pragma unroll
  for (int i = 0; i < 4; ++i)
    tile[ty + i*8][tx] = V[((size_t)h * SEQ + t0 + ty + i*8) * HD + d0 + tx];
  __syncthreads();
#pragma unroll
  for (int i = 0; i < 4; ++i)
    Vt[((size_t)h * HD + d0 + ty + i*8) * SEQ + t0 + tx] = tile[tx][ty + i*8];
}

// ---------------- merged GEMM: C[2304][3072] = A[2304][3072] x Bt^T ----------------
// bm<2 -> encoder rows (use Benc/bEnc); else image rows (Bimg/bImg).
// mode 0: out bf16 head-split [24][2304][128] (plane = bn); mode 1: fp32 with
// enc/img row remap into d_out (img rows first, then enc rows).
struct GArgs {
  const u16* A;
  const u16* Bimg0; const u16* Bimg1; const u16* Bimg2;
  const u16* Benc0; const u16* Benc1; const u16* Benc2;
  const float* bEnc0; const float* bEnc1; const float* bEnc2;
  const float* bImg;  // mode 1 image bias (null for mode 0)
  void* out0; void* out1; void* out2;
  int mode;
};

__global__ __launch_bounds__(256) void gemm_bt_k(GArgs p) {
  __shared__ __attribute__((aligned(128))) char As[128*128];
  __shared__ __attribute__((aligned(128))) char Bs[128*128];
  const int bz = blockIdx.z;
  const int bm = blockIdx.x, bn = blockIdx.y;
  const bool enc = (bm < 2);
  const u16* __restrict__ Bm = (bz == 0) ? (enc ? p.Benc0 : p.Bimg0)
                             : (bz == 1) ? (enc ? p.Benc1 : p.Bimg1)
                                         : (enc ? p.Benc2 : p.Bimg2);
  const float* __restrict__ bias = enc ? ((bz == 0) ? p.bEnc0 : (bz == 1) ? p.bEnc1 : p.bEnc2)
                                       : p.bImg;
  void* out = (bz == 0) ? p.out0 : (bz == 1) ? p.out1 : p.out2;
  const int tid = threadIdx.x;
  const int w = tid >> 6, l = tid & 63;
  const int wr = w >> 1, wc = w & 1;

  f32x4 acc[4][4];
#pragma unroll
  for (int mi = 0; mi < 4; ++mi)
#pragma unroll
    for (int ni = 0; ni < 4; ++ni) acc[mi][ni] = zero4();

  const int srow  = l >> 3;
  const int scolb = ((l & 7) ^ srow) << 4;
  const char* Ag = (const char*)(p.A + (size_t)(bm*128 + w*32) * DM) + (size_t)srow * (DM*2) + scolb;
  const char* Bg = (const char*)(Bm  + (size_t)(bn*128 + w*32) * DM) + (size_t)srow * (DM*2) + scolb;
  char* AsW = As + (w*32) * 128;
  char* BsW = Bs + (w*32) * 128;

  for (int kt = 0; kt < DM/64; ++kt) {
#pragma unroll
    for (int i = 0; i < 4; ++i) {
      GLDS16(Ag + (size_t)i*8*(DM*2) + kt*128, AsW + i*8*128);
      GLDS16(Bg + (size_t)i*8*(DM*2) + kt*128, BsW + i*8*128);
    }
    __syncthreads();
#pragma unroll
    for (int kk = 0; kk < 2; ++kk) {
      bf16x8 af[4], bfr[4];
#pragma unroll
      for (int mi = 0; mi < 4; ++mi) {
        const int row = wr*64 + mi*16 + (l & 15);
        const int cb  = ((kk << 6) + ((l >> 4) << 4)) ^ ((row & 7) << 4);
        af[mi] = *(const bf16x8*)(As + row*128 + cb);
      }
#pragma unroll
      for (int ni = 0; ni < 4; ++ni) {
        const int row = wc*64 + ni*16 + (l & 15);
        const int cb  = ((kk << 6) + ((l >> 4) << 4)) ^ ((row & 7) << 4);
        bfr[ni] = *(const bf16x8*)(Bs + row*128 + cb);
      }
#pragma unroll
      for (int mi = 0; mi < 4; ++mi)
#pragma unroll
        for (int ni = 0; ni < 4; ++ni)
          acc[mi][ni] = __builtin_amdgcn_mfma_f32_16x16x32_bf16(af[mi], bfr[ni], acc[mi][ni], 0, 0, 0);
    }
    __syncthreads();
  }

#pragma unroll
  for (int mi = 0; mi < 4; ++mi) {
    const int mbase = bm*128 + wr*64 + mi*16 + ((l >> 4) << 2);
#pragma unroll
    for (int ni = 0; ni < 4; ++ni) {
      const int ncol = bn*128 + wc*64 + ni*16 + (l & 15);
      const float bv = bias ? bias[ncol] : 0.f;
#pragma unroll
      for (int r = 0; r < 4; ++r) {
        const float v = acc[mi][ni][r] + bv;
        const int row = mbase + r;
        if (p.mode == 0) {
          ((u16*)out)[((size_t)bn * SEQ + row) * HD + (ncol & 127)] = f2bf(v);
        } else {
          const size_t orow = (row < S_TXT) ? (size_t)(S_IMG + row) : (size_t)(row - S_TXT);
          ((float*)out)[orow * DM + ncol] = v;
        }
      }
    }
  }
}

// ---------------- fused per-head RMSNorm + RoPE, bf16 out ----------------
__global__ __launch_bounds__(256) void qk_norm_rope_k(
    const u16* __restrict__ Qf, const u16* __restrict__ Kf,
    u16* __restrict__ Qb, u16* __restrict__ Kb,
    const float* __restrict__ cosT, const float* __restrict__ sinT,
    const float* __restrict__ nq, const float* __restrict__ nk,
    const float* __restrict__ naq, const float* __restrict__ nak) {
  const int gw = (blockIdx.x * 256 + threadIdx.x) >> 6;
  const int l = threadIdx.x & 63;
  const int which = (gw >= NH * SEQ) ? 1 : 0;
  const int rem = which ? (gw - NH * SEQ) : gw;
  const int h = rem / SEQ, t = rem % SEQ;
  const size_t base = ((size_t)h * SEQ + t) * HD + l * 2;
  const ushort2 xb = *(const ushort2*)((which ? Kf : Qf) + base);
  const float x0 = bf2f(xb.x), x1 = bf2f(xb.y);
  float ss = x0*x0 + x1*x1;
#pragma unroll
  for (int msk = 1; msk < 64; msk <<= 1) ss += __shfl_xor(ss, msk, 64);
  const float rr = rsqrtf(ss * (1.0f/128.0f) + 1e-6f);
  const float* nw = which ? (t < S_TXT ? nak : nk) : (t < S_TXT ? naq : nq);
  const float n0 = x0 * rr * nw[l*2], n1 = x1 * rr * nw[l*2 + 1];
  const float c = cosT[(size_t)t * HD + l*2], sn = sinT[(size_t)t * HD + l*2];
  float o0 = n0 * c - n1 * sn;
  float o1 = n1 * c + n0 * sn;
  if (!which) { o0 *= SCALE; o1 *= SCALE; }
  ushort2 ob; ob.x = f2bf(o0); ob.y = f2bf(o1);
  *(ushort2*)((which ? Kb : Qb) + base) = ob;
}

// ---------------- flash attention v3: double-buffered 2-phase pipeline ----------------
// 1D grid 432 = 8 XCDs x 54; chunked XCD swizzle -> each XCD owns 3 heads
// (K+Vt hot set 3.4MB fits its 4MB L2). 4 waves; wave w owns q rows
// [qb*128+w*32, +32) as 2 q-subtiles. Swapped QK^T (S^T = mfma(K,Q)) puts a
// kv-contiguous P row in each lane -> in-lane softmax + packed b64 P writes.
// K/V LDS double-buffered: STAGE(next) issued before compute(cur), counted
// s_waitcnt vmcnt(8) + raw s_barrier keeps next tile's loads in flight.
__global__ __launch_bounds__(256) void attn_k(
    const u16* __restrict__ Q, const u16* __restrict__ K,
    const u16* __restrict__ Vt, u16* __restrict__ O) {
  __shared__ __attribute__((aligned(128))) char Kl[2][64*256];   // 32 KB
  __shared__ __attribute__((aligned(128))) char Vl[2][128*128];  // 32 KB
  __shared__ __attribute__((aligned(128))) char Pl[4][2048];     // 8 KB (per-wave)
  const int orig = blockIdx.x;
  const int lin = (orig & 7) * 54 + (orig >> 3);   // bijective: 432 = 8*54
  const int h = lin / 18, qb = lin % 18;
  const int tid = threadIdx.x, w = tid >> 6, l = tid & 63;
  const int g = l >> 4, q16 = l & 15;
  const int NT = SEQ / 64;

  const u16* Qh = Q  + ((size_t)h * SEQ + qb*128 + w*32) * HD;
  const u16* Kh = K  + (size_t)h * SEQ * HD;
  const u16* Vh = Vt + (size_t)h * HD * SEQ;

  // Q as B-frag: col = q16 (q row), k = kf*32 + g*8 contiguous d
  bf16x8 qf[2][4];
#pragma unroll
  for (int qt = 0; qt < 2; ++qt)
#pragma unroll
    for (int kf = 0; kf < 4; ++kf)
      qf[qt][kf] = *(const bf16x8*)(Qh + (qt*16 + q16) * HD + kf*32 + g*8);

  f32x4 o[2][8];
#pragma unroll
  for (int qt = 0; qt < 2; ++qt)
#pragma unroll
    for (int db = 0; db < 8; ++db) o[qt][db] = zero4();
  float m[2]  = {-3e38f, -3e38f};
  float rl[2] = {0.f, 0.f};

  const int vswz = ((l & 7) ^ (l >> 3)) << 4;
  const int pswz = (q16 & 7) << 4;

  auto STAGE = [&](int buf, int kb) {
#pragma unroll
    for (int i = 0; i < 4; ++i) {
      const int rloc = i*4 + (l >> 4);
      const int colb = ((l & 15) << 4) ^ ((rloc & 7) << 4);
      GLDS16((const char*)Kh + ((size_t)(kb*64 + w*16 + rloc)) * 256 + colb,
             &Kl[buf][(w*16 + i*4) * 256]);
    }
#pragma unroll
    for (int i = 0; i < 4; ++i) {
      const int rloc = w*32 + i*8 + (l >> 3);
      GLDS16((const char*)Vh + (size_t)rloc * (SEQ*2) + kb*128 + vswz,
             &Vl[buf][(w*32 + i*8) * 128]);
    }
  };

  STAGE(0, 0);
  int cur = 0;

  for (int kb = 0; kb < NT; ++kb) {
    if (kb + 1 < NT) {
      STAGE(cur ^ 1, kb + 1);                        // next tile's 8 loads stay in flight
      asm volatile("s_waitcnt vmcnt(8)" ::: "memory");
    } else {
      asm volatile("s_waitcnt vmcnt(0)" ::: "memory");
    }
    __builtin_amdgcn_s_barrier();
    __builtin_amdgcn_sched_barrier(0);

    const char* Kb_ = Kl[cur];
    const char* Vb_ = Vl[cur];

    // S^T[kv][q] = K · Q^T ; K frags shared across both q-subtiles
    f32x4 s[2][4];
#pragma unroll
    for (int qt = 0; qt < 2; ++qt)
#pragma unroll
      for (int mi = 0; mi < 4; ++mi) s[qt][mi] = zero4();
    __builtin_amdgcn_s_setprio(1);
#pragma unroll
    for (int mi = 0; mi < 4; ++mi) {
      const int row = mi*16 + q16;
      bf16x8 kfr[4];
#pragma unroll
      for (int kf = 0; kf < 4; ++kf) {
        const int cb = ((kf << 6) + (g << 4)) ^ ((row & 7) << 4);
        kfr[kf] = *(const bf16x8*)(Kb_ + row*256 + cb);
      }
#pragma unroll
      for (int kf = 0; kf < 4; ++kf) {
        s[0][mi] = __builtin_amdgcn_mfma_f32_16x16x32_bf16(kfr[kf], qf[0][kf], s[0][mi], 0, 0, 0);
        s[1][mi] = __builtin_amdgcn_mfma_f32_16x16x32_bf16(kfr[kf], qf[1][kf], s[1][mi], 0, 0, 0);
      }
    }
    __builtin_amdgcn_s_setprio(0);

    // online softmax per q-subtile; P round-trip through shared per-wave Pl
    // (same-wave DS ops are ordered -> qt=1 overwrite is safe after qt=0 reads)
    float rsv[2];
    bf16x8 pa[2][2];
    char* Pw = Pl[w];
#pragma unroll
    for (int qt = 0; qt < 2; ++qt) {
      float mx = s[qt][0][0];
#pragma unroll
      for (int mi = 0; mi < 4; ++mi)
#pragma unroll
        for (int r = 0; r < 4; ++r) mx = fmaxf(mx, s[qt][mi][r]);
      mx = fmaxf(mx, __shfl_xor(mx, 16, 64));
      mx = fmaxf(mx, __shfl_xor(mx, 32, 64));
      const float mn = fmaxf(m[qt], mx);
      rsv[qt] = __expf(m[qt] - mn);
      m[qt] = mn;
      float sum = 0.f;
#pragma unroll
      for (int mi = 0; mi < 4; ++mi) {
        f32x4 t = s[qt][mi];
#pragma unroll
        for (int r = 0; r < 4; ++r) { t[r] = __expf(t[r] - mn); sum += t[r]; }
        s[qt][mi] = t;
      }
      sum += __shfl_xor(sum, 16, 64);
      sum += __shfl_xor(sum, 32, 64);
      rl[qt] = rl[qt] * rsv[qt] + sum;
#pragma unroll
      for (int mi = 0; mi < 4; ++mi) {
        uint2 pk;
        pk.x = cvtpk(s[qt][mi][0], s[qt][mi][1]);
        pk.y = cvtpk(s[qt][mi][2], s[qt][mi][3]);
        *(uint2*)(Pw + ((q16*128 + mi*32 + g*8) ^ pswz)) = pk;
      }
#pragma unroll
      for (int kblk = 0; kblk < 2; ++kblk)
        pa[qt][kblk] = *(const bf16x8*)(Pw + ((q16*128 + kblk*64 + g*16) ^ pswz));
    }

    // rescale O (C-layout q = g*4 + r)
#pragma unroll
    for (int qt = 0; qt < 2; ++qt) {
      float rs4[4];
#pragma unroll
      for (int r = 0; r < 4; ++r)
        rs4[r] = __shfl(rsv[qt], (g << 4) + (g << 2) + r, 64);
#pragma unroll
      for (int db = 0; db < 8; ++db) {
        f32x4 t = o[qt][db];
#pragma unroll
        for (int r = 0; r < 4; ++r) t[r] *= rs4[r];
        o[qt][db] = t;
      }
    }

    // O += P · V ; Vt B-frags shared across both q-subtiles
    __builtin_amdgcn_s_setprio(1);
#pragma unroll
    for (int kblk = 0; kblk < 2; ++kblk)
#pragma unroll
      for (int db = 0; db < 8; ++db) {
        const int vrow = db*16 + q16;
        const int vcb  = ((kblk << 6) + (g << 4)) ^ ((vrow & 7) << 4);
        bf16x8 vb = *(const bf16x8*)(Vb_ + vrow*128 + vcb);
        o[0][db] = __builtin_amdgcn_mfma_f32_16x16x32_bf16(pa[0][kblk], vb, o[0][db], 0, 0, 0);
        o[1][db] = __builtin_amdgcn_mfma_f32_16x16x32_bf16(pa[1][kblk], vb, o[1][db], 0, 0, 0);
      }
    __builtin_amdgcn_s_setprio(0);

    asm volatile("s_waitcnt lgkmcnt(0)" ::: "memory");
    __builtin_amdgcn_s_barrier();
    __builtin_amdgcn_sched_barrier(0);
    cur ^= 1;
  }

  // epilogue
#pragma unroll
  for (int qt = 0; qt < 2; ++qt) {
    float inv4[4];
#pragma unroll
    for (int r = 0; r < 4; ++r)
      inv4[r] = 1.f / __shfl(rl[qt], (g << 4) + (g << 2) + r, 64);
#pragma unroll
    for (int db = 0; db < 8; ++db)
#pragma unroll
      for (int r = 0; r < 4; ++r) {
        const int token = qb*128 + w*32 + qt*16 + g*4 + r;
        const int col = h*HD + db*16 + q16;
        O[(size_t)token * DM + col] = f2bf(o[qt][db][r] * inv4[r]);
      }
  }
}

// ---------------- host ----------------
extern "C" void kernel_launch(void* const* d_in, const int* in_sizes, int n_in,
                              void* d_out, int out_size, void* d_ws, size_t ws_size,
                              hipStream_t stream) {
  const float* hidden = (const float*)d_in[0];
  const float* ench   = (const float*)d_in[1];
  const float* cosT   = (const float*)d_in[2];
  const float* sinT   = (const float*)d_in[3];
  const float* wq  = (const float*)d_in[4];
  const float* wk  = (const float*)d_in[5];
  const float* wv  = (const float*)d_in[6];
  const float* wqa = (const float*)d_in[7];
  const float* wka = (const float*)d_in[8];
  const float* wva = (const float*)d_in[9];
  const float* bqa = (const float*)d_in[10];
  const float* bka = (const float*)d_in[11];
  const float* bva = (const float*)d_in[12];
  const float* nq  = (const float*)d_in[13];
  const float* nk  = (const float*)d_in[14];
  const float* naq = (const float*)d_in[15];
  const float* nak = (const float*)d_in[16];
  const float* w_out     = (const float*)d_in[17];
  const float* b_out     = (const float*)d_in[18];
  const float* w_add_out = (const float*)d_in[19];
  const float* b_add_out = (const float*)d_in[20];
  float* outp = (float*)d_out;
  (void)in_sizes; (void)n_in; (void)out_size; (void)ws_size;

  char* ws = (char*)d_ws;
  size_t off = 0;
  auto alloc = [&](size_t n) { char* p = ws + off; off += (n + 255) & ~(size_t)255; return p; };
  u16* wt[8];
  for (int i = 0; i < 8; ++i) wt[i] = (u16*)alloc((size_t)DM * DM * 2);
  u16* xb = (u16*)alloc((size_t)SEQ * DM * 2);   // enc rows [0,256) then img
  u16* Qf = (u16*)alloc((size_t)NH * SEQ * HD * 2);
  u16* Kf = (u16*)alloc((size_t)NH * SEQ * HD * 2);
  u16* Vf = (u16*)alloc((size_t)NH * SEQ * HD * 2);
  u16* Qb = (u16*)alloc((size_t)NH * SEQ * HD * 2);
  u16* Kb = (u16*)alloc((size_t)NH * SEQ * HD * 2);
  u16* Vt = (u16*)alloc((size_t)NH * HD * SEQ * 2);
  u16* Ob = (u16*)alloc((size_t)SEQ * DM * 2);

  conv_bf16_k<<<(S_TXT*DM/4)/256, 256, 0, stream>>>(ench, xb, S_TXT*DM/4);
  conv_bf16_k<<<(S_IMG*DM/4)/256, 256, 0, stream>>>(hidden, xb + (size_t)S_TXT*DM, S_IMG*DM/4);

  WP wp;
  wp.s[0] = wq;  wp.s[1] = wk;  wp.s[2] = wv;
  wp.s[3] = wqa; wp.s[4] = wka; wp.s[5] = wva;
  wp.s[6] = w_out; wp.s[7] = w_add_out;
  for (int i = 0; i < 8; ++i) wp.d[i] = wt[i];
  w_transpose_k<<<dim3(96, 96, 8), 256, 0, stream>>>(wp);

  // merged QKV projection (enc rows = m-tiles 0,1)
  GArgs qkv;
  qkv.A = xb;
  qkv.Bimg0 = wt[0]; qkv.Bimg1 = wt[1]; qkv.Bimg2 = wt[2];
  qkv.Benc0 = wt[3]; qkv.Benc1 = wt[4]; qkv.Benc2 = wt[5];
  qkv.bEnc0 = bqa;   qkv.bEnc1 = bka;   qkv.bEnc2 = bva;
  qkv.bImg  = nullptr;
  qkv.out0 = Qf; qkv.out1 = Kf; qkv.out2 = Vf;
  qkv.mode = 0;
  gemm_bt_k<<<dim3(18, 24, 3), 256, 0, stream>>>(qkv);

  qk_norm_rope_k<<<(2*NH*SEQ)/4, 256, 0, stream>>>(Qf, Kf, Qb, Kb, cosT, sinT, nq, nk, naq, nak);
  v_transpose_k<<<dim3(SEQ/32, HD/32, NH), 256, 0, stream>>>(Vf, Vt);

  attn_k<<<432, 256, 0, stream>>>(Qb, Kb, Vt, Ob);

  // merged output projection (img rows -> d_out head, enc rows -> tail)
  GArgs op;
  op.A = Ob;
  op.Bimg0 = wt[6]; op.Bimg1 = wt[6]; op.Bimg2 = wt[6];
  op.Benc0 = wt[7]; op.Benc1 = wt[7]; op.Benc2 = wt[7];
  op.bEnc0 = b_add_out; op.bEnc1 = b_add_out; op.bEnc2 = b_add_out;
  op.bImg  = b_out;
  op.out0 = outp; op.out1 = outp; op.out2 = outp;
  op.mode = 1;
  gemm_bt_k<<<dim3(18, 24, 1), 256, 0, stream>>>(op);
}